// Round 6
// baseline (298.064 us; speedup 1.0000x reference)
//
#include <hip/hip_runtime.h>
#include <hip/hip_bf16.h>

#define DIM 1024
#define NUM_HEADS 16
#define HEAD_DIM 64
#define BATCH 2
#define SEQ 2048
#define M_ROWS (BATCH * SEQ)   // 4096

typedef short bh8 __attribute__((ext_vector_type(8)));   // 8 bf16 (4 VGPRs)
typedef float f32x4 __attribute__((ext_vector_type(4)));

__device__ __forceinline__ ushort f2bf(float f) {
    union { float f; unsigned u; } v; v.f = f;
    unsigned u = v.u;
    unsigned r = (u + 0x7FFFu + ((u >> 16) & 1u)) >> 16;
    return (ushort)r;
}

__device__ __forceinline__ ushort2 pk_bf16(float a, float b) {
#if __has_builtin(__builtin_amdgcn_cvt_pk_bf16_f32)
    auto r = __builtin_amdgcn_cvt_pk_bf16_f32(a, b);
    ushort2 o; __builtin_memcpy(&o, &r, 4); return o;
#else
    ushort2 o; o.x = f2bf(a); o.y = f2bf(b); return o;
#endif
}

// async global->LDS 16B copy; LDS dest is wave-uniform base + lane*16
__device__ __forceinline__ void async_cp16(const ushort* g, ushort* l) {
    __builtin_amdgcn_global_load_lds(
        (const __attribute__((address_space(1))) void*)(uintptr_t)g,
        (__attribute__((address_space(3))) void*)(uint32_t)(uintptr_t)l,
        16, 0, 0);
}

// ---------------- cast x: fp32 -> bf16 ----------------
__global__ __launch_bounds__(256) void cast_x(const float* __restrict__ in,
                                              ushort* __restrict__ out, int n4) {
    int i = blockIdx.x * 256 + threadIdx.x;
    if (i < n4) {
        float4 v = ((const float4*)in)[i];
        ushort4 o;
        o.x = f2bf(v.x); o.y = f2bf(v.y); o.z = f2bf(v.z); o.w = f2bf(v.w);
        ((ushort4*)out)[i] = o;
    }
}

// ------- transpose+cast all four W [K,N] fp32 -> Wt [N,K] bf16 (z picks W) -------
__global__ __launch_bounds__(256) void transpose_cast4(
    const float* __restrict__ W0, const float* __restrict__ W1,
    const float* __restrict__ W2, const float* __restrict__ W3,
    ushort* __restrict__ T0, ushort* __restrict__ T1,
    ushort* __restrict__ T2, ushort* __restrict__ T3)
{
    __shared__ float tile[32][33];
    const int z = blockIdx.z;
    const float* W = (z == 0) ? W0 : (z == 1) ? W1 : (z == 2) ? W2 : W3;
    ushort* Wt = (z == 0) ? T0 : (z == 1) ? T1 : (z == 2) ? T2 : T3;
    const int t = threadIdx.x;
    const int tx = t & 31, ty = t >> 5;            // ty 0..7
    const int k0 = blockIdx.y * 32, n0 = blockIdx.x * 32;
    #pragma unroll
    for (int i = 0; i < 4; ++i)
        tile[ty + 8 * i][tx] = W[(size_t)(k0 + ty + 8 * i) * DIM + n0 + tx];
    __syncthreads();
    #pragma unroll
    for (int i = 0; i < 4; ++i)
        Wt[(size_t)(n0 + ty + 8 * i) * DIM + k0 + tx] = f2bf(tile[tx][ty + 8 * i]);
}

// ---------------- shared MFMA GEMM core: 128x128 tile, BK=64 ----------------
// C = A[M,1024] @ Bt[N,1024]^T. LDS dense + xor swizzle (chunk c at row r -> phys c^(r&7)).
#define GTM 128
#define GTN 128
#define GBK 64

__device__ __forceinline__ void gemm_core(
    const ushort* __restrict__ A, const ushort* __restrict__ Bt,
    ushort* smem, int m0, int n0, int t, f32x4 acc[4][4])
{
    ushort* As = smem;          // 128*64 ushorts = 16 KB
    ushort* Bs = smem + 8192;   // 128*64 ushorts = 16 KB
    const int lane = t & 63, wave = t >> 6;
    const int col = lane & 15, quad = lane >> 4;
    const int wm = (wave & 1) * 64, wn = (wave >> 1) * 64;

    for (int k0 = 0; k0 < DIM; k0 += GBK) {
        __syncthreads();
        #pragma unroll
        for (int j = 0; j < 4; ++j) {              // A: 1024 chunks, 4 issues/wave
            int C = wave * 256 + j * 64 + lane;
            int row = C >> 3;
            int lch = (C & 7) ^ (row & 7);
            async_cp16(&A[(size_t)(m0 + row) * DIM + k0 + lch * 8],
                       &As[(wave * 256 + j * 64) * 8]);
        }
        #pragma unroll
        for (int j = 0; j < 4; ++j) {              // B: 1024 chunks, 4 issues/wave
            int C = wave * 256 + j * 64 + lane;
            int row = C >> 3;
            int lch = (C & 7) ^ (row & 7);
            async_cp16(&Bt[(size_t)(n0 + row) * DIM + k0 + lch * 8],
                       &Bs[(wave * 256 + j * 64) * 8]);
        }
        __syncthreads();
        #pragma unroll
        for (int kk = 0; kk < 2; ++kk) {
            bh8 af[4], bf[4];
            #pragma unroll
            for (int mi = 0; mi < 4; ++mi) {
                int row = wm + mi * 16 + col;
                af[mi] = *(const bh8*)&As[row * 64 + (((kk * 4 + quad) ^ (row & 7)) * 8)];
            }
            #pragma unroll
            for (int ni = 0; ni < 4; ++ni) {
                int row = wn + ni * 16 + col;
                bf[ni] = *(const bh8*)&Bs[row * 64 + (((kk * 4 + quad) ^ (row & 7)) * 8)];
            }
            #pragma unroll
            for (int mi = 0; mi < 4; ++mi)
                #pragma unroll
                for (int ni = 0; ni < 4; ++ni)
                    acc[mi][ni] = __builtin_amdgcn_mfma_f32_16x16x32_bf16(
                        af[mi], bf[ni], acc[mi][ni], 0, 0, 0);
        }
    }
}

// ---------------- fused QKV projection ----------------
// z=0: Q (head layout), z=1: K (head layout), z=2: V (transposed head layout)
__global__ __launch_bounds__(256) void gemm_qkv(
    const ushort* __restrict__ A,
    const ushort* __restrict__ WqT, const ushort* __restrict__ WkT,
    const ushort* __restrict__ WvT,
    const float* __restrict__ bq, const float* __restrict__ bk,
    const float* __restrict__ bv,
    ushort* __restrict__ qo, ushort* __restrict__ ko_, ushort* __restrict__ vo)
{
    __shared__ ushort smem[17408];   // max(32 KB staging, 128x136 epilogue)
    const int z = blockIdx.z;
    const ushort* Bt = (z == 0) ? WqT : (z == 1) ? WkT : WvT;
    const float* bias = (z == 0) ? bq : (z == 1) ? bk : bv;
    ushort* outp = (z == 0) ? qo : (z == 1) ? ko_ : vo;

    const int t = threadIdx.x;
    const int lane = t & 63, wave = t >> 6;
    const int col = lane & 15, quad = lane >> 4;
    const int m0 = blockIdx.y * GTM, n0 = blockIdx.x * GTN;
    const int wm = (wave & 1) * 64, wn = (wave >> 1) * 64;
    f32x4 acc[4][4] = {};

    gemm_core(A, Bt, smem, m0, n0, t, acc);

    const int b = m0 >> 11, s0 = m0 & (SEQ - 1);
    const int h0 = n0 >> 6;
    __syncthreads();
    ushort* LT = smem;                              // [128][136]

    if (z < 2) {
        // LT[m][n], then coalesced 16B stores into [B,H,S,64]
        #pragma unroll
        for (int mi = 0; mi < 4; ++mi)
            #pragma unroll
            for (int ni = 0; ni < 4; ++ni) {
                int dl = wn + ni * 16 + col;
                float bvv = bias[n0 + dl];
                #pragma unroll
                for (int r = 0; r < 4; ++r)
                    LT[(wm + mi * 16 + quad * 4 + r) * 136 + dl] = f2bf(acc[mi][ni][r] + bvv);
            }
        __syncthreads();
        #pragma unroll
        for (int i = 0; i < 8; ++i) {               // 2048 chunks of 8
            int c = i * 256 + t;
            int row = c >> 4;                       // m-local 0..127
            int dcol = (c & 15) * 8;                // 0..120
            int h = h0 + (dcol >> 6);
            *(uint4*)&outp[(((size_t)(b * NUM_HEADS + h) * SEQ) + s0 + row) * 64 + (dcol & 63)] =
                *(const uint4*)&LT[row * 136 + dcol];
        }
    } else {
        // LT[n][m] (transposed), stores into [B,H,64,S]
        #pragma unroll
        for (int mi = 0; mi < 4; ++mi)
            #pragma unroll
            for (int ni = 0; ni < 4; ++ni) {
                int nl = wn + ni * 16 + col;
                float bvv = bias[n0 + nl];
                #pragma unroll
                for (int r = 0; r < 4; ++r)
                    LT[nl * 136 + (wm + mi * 16 + quad * 4 + r)] = f2bf(acc[mi][ni][r] + bvv);
            }
        __syncthreads();
        #pragma unroll
        for (int i = 0; i < 8; ++i) {               // 2048 chunks of 8
            int c = i * 256 + t;
            int row = c >> 4;                       // n-local (d) 0..127
            int moff = (c & 15) * 8;                // 0..120
            int h = h0 + (row >> 6);
            *(uint4*)&outp[(((size_t)(b * NUM_HEADS + h) * HEAD_DIM) + (row & 63)) * SEQ + s0 + moff] =
                *(const uint4*)&LT[row * 136 + moff];
        }
    }
}

// ---------------- output projection: fp32 out ----------------
__global__ __launch_bounds__(256) void gemm_out(
    const ushort* __restrict__ A, const ushort* __restrict__ Bt,
    const float* __restrict__ bias, float* __restrict__ C)
{
    __shared__ ushort smem[16384];
    const int t = threadIdx.x;
    const int lane = t & 63, wave = t >> 6;
    const int col = lane & 15, quad = lane >> 4;
    const int m0 = blockIdx.y * GTM, n0 = blockIdx.x * GTN;
    const int wm = (wave & 1) * 64, wn = (wave >> 1) * 64;
    f32x4 acc[4][4] = {};

    gemm_core(A, Bt, smem, m0, n0, t, acc);

    #pragma unroll
    for (int mi = 0; mi < 4; ++mi)
        #pragma unroll
        for (int ni = 0; ni < 4; ++ni) {
            int n = n0 + wn + ni * 16 + col;
            float bvv = bias[n];
            #pragma unroll
            for (int r = 0; r < 4; ++r) {
                int m = m0 + wm + mi * 16 + quad * 4 + r;
                C[(size_t)m * DIM + n] = acc[mi][ni][r] + bvv;
            }
        }
}

// ---------------- MFMA flash attention: wave-autonomous, no barriers ----------------
// 1 block = 1 wave (64 threads) = 32 queries. K/V fragments loaded DIRECTLY from
// global (L2-resident: 512 KB/head, reused by 64 waves) — no LDS staging, no
// __syncthreads, no DMA drains. Latency hidden by ~8 independent blocks/CU.
// LDS only for the P C-layout -> A-layout round-trip (4.6 KB).
#define PSTR 72

__global__ __launch_bounds__(64) void attn_mfma(
    const ushort* __restrict__ Qg, const ushort* __restrict__ Kg,
    const ushort* __restrict__ Vtg, ushort* __restrict__ ctx)
{
    __shared__ ushort Pw[32 * PSTR];          // 4608 B

    const int lane = threadIdx.x;
    const int col = lane & 15, quad = lane >> 4;
    const int qtile = blockIdx.x & 63;        // fast: same-bh waves cluster across XCDs
    const int bh = blockIdx.x >> 6;
    const int b = bh >> 4, h = bh & 15;
    const int qw = qtile * 32;
    const ushort* Kp = Kg + ((size_t)bh << 17);
    const ushort* Vp = Vtg + ((size_t)bh << 17);
    const float SCL = 0.18033688011116016f;   // 0.125 * log2(e)

    // Q fragments (B-operand): 32 queries, 2 col-tiles x 2 kk
    bh8 qf[2][2];
    #pragma unroll
    for (int ni = 0; ni < 2; ++ni) {
        const ushort* Qp = Qg + ((size_t)bh << 17) + ((size_t)(qw + ni * 16 + col) << 6) + quad * 8;
        qf[ni][0] = *(const bh8*)(Qp);
        qf[ni][1] = *(const bh8*)(Qp + 32);
    }
    float l0 = 0.f, l1 = 0.f;
    f32x4 O[4][2] = {};
    const int nIter = (qtile >> 1) + 1;

    #pragma unroll 1
    for (int it = 0; it < nIter; ++it) {
        const int kb = it * 64;

        // St = K @ Q^T : row=key, col=query. K frags direct from global.
        f32x4 St[4][2] = {};
        #pragma unroll
        for (int kk = 0; kk < 2; ++kk) {
            #pragma unroll
            for (int kt = 0; kt < 4; ++kt) {
                bh8 kf = *(const bh8*)&Kp[((size_t)(kb + kt * 16 + col) << 6) + kk * 32 + quad * 8];
                St[kt][0] = __builtin_amdgcn_mfma_f32_16x16x32_bf16(kf, qf[0][kk], St[kt][0], 0, 0, 0);
                St[kt][1] = __builtin_amdgcn_mfma_f32_16x16x32_bf16(kf, qf[1][kk], St[kt][1], 0, 0, 0);
            }
        }

        // causal mask: only the last (diagonal) key-block
        if (it == nIter - 1) {
            #pragma unroll
            for (int ni = 0; ni < 2; ++ni) {
                int q_abs = qw + ni * 16 + col;
                #pragma unroll
                for (int kt = 0; kt < 4; ++kt)
                    #pragma unroll
                    for (int r = 0; r < 4; ++r)
                        if (kb + kt * 16 + quad * 4 + r > q_abs) St[kt][ni][r] = -1e30f;
            }
        }

        // one-pass softmax (scores bounded; no running max needed)
        float lb0 = 0.f, lb1 = 0.f;
        #pragma unroll
        for (int kt = 0; kt < 4; ++kt) {
            #pragma unroll
            for (int ni = 0; ni < 2; ++ni) {
                float p0 = exp2f(St[kt][ni][0] * SCL);
                float p1 = exp2f(St[kt][ni][1] * SCL);
                float p2 = exp2f(St[kt][ni][2] * SCL);
                float p3 = exp2f(St[kt][ni][3] * SCL);
                if (ni) lb1 += (p0 + p1) + (p2 + p3);
                else    lb0 += (p0 + p1) + (p2 + p3);
                ushort2 a01 = pk_bf16(p0, p1), a23 = pk_bf16(p2, p3);
                ushort4 pk4; pk4.x = a01.x; pk4.y = a01.y; pk4.z = a23.x; pk4.w = a23.y;
                *(ushort4*)&Pw[(ni * 16 + col) * PSTR + kt * 16 + quad * 4] = pk4;   // P^T [q][key]
            }
        }
        lb0 += __shfl_xor(lb0, 16); lb0 += __shfl_xor(lb0, 32);
        lb1 += __shfl_xor(lb1, 16); lb1 += __shfl_xor(lb1, 32);
        l0 += lb0; l1 += lb1;

        // ctx^T += V^T @ P^T. V frags direct from global; P from wave-local LDS
        // (same-wave ds ordering, no barrier).
        #pragma unroll
        for (int kk = 0; kk < 2; ++kk) {
            int koff = kk * 32 + quad * 8;
            bh8 pf0 = *(const bh8*)&Pw[col * PSTR + koff];
            bh8 pf1 = *(const bh8*)&Pw[(16 + col) * PSTR + koff];
            #pragma unroll
            for (int dt = 0; dt < 4; ++dt) {
                bh8 vf = *(const bh8*)&Vp[((size_t)(dt * 16 + col) << 11) + kb + koff];
                O[dt][0] = __builtin_amdgcn_mfma_f32_16x16x32_bf16(vf, pf0, O[dt][0], 0, 0, 0);
                O[dt][1] = __builtin_amdgcn_mfma_f32_16x16x32_bf16(vf, pf1, O[dt][1], 0, 0, 0);
            }
        }
    }

    // epilogue: O (row=d, col=q) -> LDS [q][d] -> coalesced 16B global stores
    float inv0 = 1.f / l0, inv1 = 1.f / l1;
    #pragma unroll
    for (int dt = 0; dt < 4; ++dt)
        #pragma unroll
        for (int ni = 0; ni < 2; ++ni) {
            float inv = ni ? inv1 : inv0;
            ushort2 a01 = pk_bf16(O[dt][ni][0] * inv, O[dt][ni][1] * inv);
            ushort2 a23 = pk_bf16(O[dt][ni][2] * inv, O[dt][ni][3] * inv);
            ushort4 pk4; pk4.x = a01.x; pk4.y = a01.y; pk4.z = a23.x; pk4.w = a23.y;
            *(ushort4*)&Pw[(ni * 16 + col) * PSTR + dt * 16 + quad * 4] = pk4;
        }
    #pragma unroll
    for (int i = 0; i < 4; ++i) {             // 256 chunks of 8, 4/lane
        int c = i * 64 + lane;
        int row = c >> 3, ko = (c & 7) * 8;
        *(uint4*)&ctx[((size_t)(b * SEQ) + qw + row) * DIM + (h << 6) + ko] =
            *(const uint4*)&Pw[row * PSTR + ko];
    }
}

// ---------------- launch ----------------
extern "C" void kernel_launch(void* const* d_in, const int* in_sizes, int n_in,
                              void* d_out, int out_size, void* d_ws, size_t ws_size,
                              hipStream_t stream) {
    const float* x  = (const float*)d_in[0];
    const float* Wq = (const float*)d_in[1];
    const float* bq = (const float*)d_in[2];
    const float* Wk = (const float*)d_in[3];
    const float* bk = (const float*)d_in[4];
    const float* Wv = (const float*)d_in[5];
    const float* bv = (const float*)d_in[6];
    const float* Wo = (const float*)d_in[7];
    const float* bo = (const float*)d_in[8];
    float* out = (float*)d_out;

    ushort* x_bf   = (ushort*)d_ws;              // 4M elems
    ushort* wq_t   = x_bf + 4194304;             // 1M each
    ushort* wk_t   = wq_t + 1048576;
    ushort* wv_t   = wk_t + 1048576;
    ushort* wo_t   = wv_t + 1048576;
    ushort* q_ws   = wo_t + 1048576;             // [B,H,S,64] 4M
    ushort* k_ws   = q_ws + 4194304;
    ushort* vt_ws  = k_ws + 4194304;             // [B,H,64,S] 4M
    ushort* ctx_ws = vt_ws + 4194304;            // [B,S,DIM]  4M

    cast_x<<<4096, 256, 0, stream>>>(x, x_bf, (M_ROWS * DIM) / 4);
    dim3 tgrid(32, 32, 4);
    transpose_cast4<<<tgrid, 256, 0, stream>>>(Wq, Wk, Wv, Wo, wq_t, wk_t, wv_t, wo_t);

    dim3 qkv_grid(DIM / GTN, M_ROWS / GTM, 3);   // (8, 32, 3) = 768 blocks
    gemm_qkv<<<qkv_grid, 256, 0, stream>>>(x_bf, wq_t, wk_t, wv_t,
                                           bq, bk, bv, q_ws, k_ws, vt_ws);

    attn_mfma<<<BATCH * NUM_HEADS * 64, 64, 0, stream>>>(q_ws, k_ws, vt_ws, ctx_ws);

    dim3 ogrid(DIM / GTN, M_ROWS / GTM);         // (8, 32)
    gemm_out<<<ogrid, 256, 0, stream>>>(ctx_ws, wo_t, bo, out);
}

// Round 7
// 215.379 us; speedup vs baseline: 1.3839x; 1.3839x over previous
//
#include <hip/hip_runtime.h>
#include <hip/hip_bf16.h>

#define DIM 1024
#define NUM_HEADS 16
#define HEAD_DIM 64
#define BATCH 2
#define SEQ 2048
#define M_ROWS (BATCH * SEQ)   // 4096

typedef short bh8 __attribute__((ext_vector_type(8)));   // 8 bf16 (4 VGPRs)
typedef float f32x4 __attribute__((ext_vector_type(4)));

#define SCALE_Q 0.18033688011116016f   // 0.125 * log2(e), folded into Q projection

__device__ __forceinline__ ushort f2bf(float f) {
    union { float f; unsigned u; } v; v.f = f;
    unsigned u = v.u;
    unsigned r = (u + 0x7FFFu + ((u >> 16) & 1u)) >> 16;
    return (ushort)r;
}

__device__ __forceinline__ ushort2 pk_bf16(float a, float b) {
#if __has_builtin(__builtin_amdgcn_cvt_pk_bf16_f32)
    auto r = __builtin_amdgcn_cvt_pk_bf16_f32(a, b);
    ushort2 o; __builtin_memcpy(&o, &r, 4); return o;
#else
    ushort2 o; o.x = f2bf(a); o.y = f2bf(b); return o;
#endif
}

// async global->LDS 16B copy; LDS dest is wave-uniform base + lane*16
__device__ __forceinline__ void async_cp16(const ushort* g, ushort* l) {
    __builtin_amdgcn_global_load_lds(
        (const __attribute__((address_space(1))) void*)(uintptr_t)g,
        (__attribute__((address_space(3))) void*)(uint32_t)(uintptr_t)l,
        16, 0, 0);
}

// ------- fused prep: z<4 -> transpose+cast W_z [K,N]->[N,K] bf16; z==4 -> cast x -------
__global__ __launch_bounds__(256) void prep_inputs(
    const float* __restrict__ W0, const float* __restrict__ W1,
    const float* __restrict__ W2, const float* __restrict__ W3,
    const float* __restrict__ x,
    ushort* __restrict__ T0, ushort* __restrict__ T1,
    ushort* __restrict__ T2, ushort* __restrict__ T3,
    ushort* __restrict__ xb)
{
    const int z = blockIdx.z;
    const int t = threadIdx.x;
    if (z == 4) {
        int base = (blockIdx.y * 32 + blockIdx.x) * 1024 + t;   // float4 index
        const float4* in4 = (const float4*)x;
        ushort4* out4 = (ushort4*)xb;
        #pragma unroll
        for (int i = 0; i < 4; ++i) {
            float4 v = in4[base + i * 256];
            ushort4 o;
            o.x = f2bf(v.x); o.y = f2bf(v.y); o.z = f2bf(v.z); o.w = f2bf(v.w);
            out4[base + i * 256] = o;
        }
        return;
    }
    __shared__ float tile[32][33];
    const float* W = (z == 0) ? W0 : (z == 1) ? W1 : (z == 2) ? W2 : W3;
    ushort* Wt = (z == 0) ? T0 : (z == 1) ? T1 : (z == 2) ? T2 : T3;
    const int tx = t & 31, ty = t >> 5;            // ty 0..7
    const int k0 = blockIdx.y * 32, n0 = blockIdx.x * 32;
    #pragma unroll
    for (int i = 0; i < 4; ++i)
        tile[ty + 8 * i][tx] = W[(size_t)(k0 + ty + 8 * i) * DIM + n0 + tx];
    __syncthreads();
    #pragma unroll
    for (int i = 0; i < 4; ++i)
        Wt[(size_t)(n0 + ty + 8 * i) * DIM + k0 + tx] = f2bf(tile[tx][ty + 8 * i]);
}

// ---------------- shared MFMA GEMM core: 128x128 tile, BK=64 ----------------
// C = A[M,1024] @ Bt[N,1024]^T. LDS dense + xor swizzle (chunk c at row r -> phys c^(r&7)).
#define GTM 128
#define GTN 128
#define GBK 64

__device__ __forceinline__ void gemm_core(
    const ushort* __restrict__ A, const ushort* __restrict__ Bt,
    ushort* smem, int m0, int n0, int t, f32x4 acc[4][4])
{
    ushort* As = smem;          // 128*64 ushorts = 16 KB
    ushort* Bs = smem + 8192;   // 128*64 ushorts = 16 KB
    const int lane = t & 63, wave = t >> 6;
    const int col = lane & 15, quad = lane >> 4;
    const int wm = (wave & 1) * 64, wn = (wave >> 1) * 64;

    for (int k0 = 0; k0 < DIM; k0 += GBK) {
        __syncthreads();
        #pragma unroll
        for (int j = 0; j < 4; ++j) {              // A: 1024 chunks, 4 issues/wave
            int C = wave * 256 + j * 64 + lane;
            int row = C >> 3;
            int lch = (C & 7) ^ (row & 7);
            async_cp16(&A[(size_t)(m0 + row) * DIM + k0 + lch * 8],
                       &As[(wave * 256 + j * 64) * 8]);
        }
        #pragma unroll
        for (int j = 0; j < 4; ++j) {              // B: 1024 chunks, 4 issues/wave
            int C = wave * 256 + j * 64 + lane;
            int row = C >> 3;
            int lch = (C & 7) ^ (row & 7);
            async_cp16(&Bt[(size_t)(n0 + row) * DIM + k0 + lch * 8],
                       &Bs[(wave * 256 + j * 64) * 8]);
        }
        __syncthreads();
        #pragma unroll
        for (int kk = 0; kk < 2; ++kk) {
            bh8 af[4], bf[4];
            #pragma unroll
            for (int mi = 0; mi < 4; ++mi) {
                int row = wm + mi * 16 + col;
                af[mi] = *(const bh8*)&As[row * 64 + (((kk * 4 + quad) ^ (row & 7)) * 8)];
            }
            #pragma unroll
            for (int ni = 0; ni < 4; ++ni) {
                int row = wn + ni * 16 + col;
                bf[ni] = *(const bh8*)&Bs[row * 64 + (((kk * 4 + quad) ^ (row & 7)) * 8)];
            }
            #pragma unroll
            for (int mi = 0; mi < 4; ++mi)
                #pragma unroll
                for (int ni = 0; ni < 4; ++ni)
                    acc[mi][ni] = __builtin_amdgcn_mfma_f32_16x16x32_bf16(
                        af[mi], bf[ni], acc[mi][ni], 0, 0, 0);
        }
    }
}

// ---------------- fused QKV projection ----------------
// z=0: Q (head layout, pre-scaled by SCALE_Q), z=1: K (head layout), z=2: V (transposed)
__global__ __launch_bounds__(256) void gemm_qkv(
    const ushort* __restrict__ A,
    const ushort* __restrict__ WqT, const ushort* __restrict__ WkT,
    const ushort* __restrict__ WvT,
    const float* __restrict__ bq, const float* __restrict__ bk,
    const float* __restrict__ bv,
    ushort* __restrict__ qo, ushort* __restrict__ ko_, ushort* __restrict__ vo)
{
    __shared__ ushort smem[17408];   // max(32 KB staging, 128x136 epilogue)
    const int z = blockIdx.z;
    const ushort* Bt = (z == 0) ? WqT : (z == 1) ? WkT : WvT;
    const float* bias = (z == 0) ? bq : (z == 1) ? bk : bv;
    ushort* outp = (z == 0) ? qo : (z == 1) ? ko_ : vo;

    const int t = threadIdx.x;
    const int lane = t & 63, wave = t >> 6;
    const int col = lane & 15, quad = lane >> 4;
    const int m0 = blockIdx.y * GTM, n0 = blockIdx.x * GTN;
    const int wm = (wave & 1) * 64, wn = (wave >> 1) * 64;
    f32x4 acc[4][4] = {};

    gemm_core(A, Bt, smem, m0, n0, t, acc);

    const int b = m0 >> 11, s0 = m0 & (SEQ - 1);
    const int h0 = n0 >> 6;
    __syncthreads();
    ushort* LT = smem;                              // [128][136]

    if (z < 2) {
        const float scl = (z == 0) ? SCALE_Q : 1.f;
        // LT[m][n], then coalesced 16B stores into [B,H,S,64]
        #pragma unroll
        for (int mi = 0; mi < 4; ++mi)
            #pragma unroll
            for (int ni = 0; ni < 4; ++ni) {
                int dl = wn + ni * 16 + col;
                float bvv = bias[n0 + dl];
                #pragma unroll
                for (int r = 0; r < 4; ++r)
                    LT[(wm + mi * 16 + quad * 4 + r) * 136 + dl] =
                        f2bf((acc[mi][ni][r] + bvv) * scl);
            }
        __syncthreads();
        #pragma unroll
        for (int i = 0; i < 8; ++i) {               // 2048 chunks of 8
            int c = i * 256 + t;
            int row = c >> 4;                       // m-local 0..127
            int dcol = (c & 15) * 8;                // 0..120
            int h = h0 + (dcol >> 6);
            *(uint4*)&outp[(((size_t)(b * NUM_HEADS + h) * SEQ) + s0 + row) * 64 + (dcol & 63)] =
                *(const uint4*)&LT[row * 136 + dcol];
        }
    } else {
        // LT[n][m] (transposed), stores into [B,H,64,S]
        #pragma unroll
        for (int mi = 0; mi < 4; ++mi)
            #pragma unroll
            for (int ni = 0; ni < 4; ++ni) {
                int nl = wn + ni * 16 + col;
                float bvv = bias[n0 + nl];
                #pragma unroll
                for (int r = 0; r < 4; ++r)
                    LT[nl * 136 + (wm + mi * 16 + quad * 4 + r)] = f2bf(acc[mi][ni][r] + bvv);
            }
        __syncthreads();
        #pragma unroll
        for (int i = 0; i < 8; ++i) {               // 2048 chunks of 8
            int c = i * 256 + t;
            int row = c >> 4;                       // n-local (d) 0..127
            int moff = (c & 15) * 8;                // 0..120
            int h = h0 + (row >> 6);
            *(uint4*)&outp[(((size_t)(b * NUM_HEADS + h) * HEAD_DIM) + (row & 63)) * SEQ + s0 + moff] =
                *(const uint4*)&LT[row * 136 + moff];
        }
    }
}

// ---------------- output projection: fp32 out ----------------
__global__ __launch_bounds__(256) void gemm_out(
    const ushort* __restrict__ A, const ushort* __restrict__ Bt,
    const float* __restrict__ bias, float* __restrict__ C)
{
    __shared__ ushort smem[16384];
    const int t = threadIdx.x;
    const int lane = t & 63, wave = t >> 6;
    const int col = lane & 15, quad = lane >> 4;
    const int m0 = blockIdx.y * GTM, n0 = blockIdx.x * GTN;
    const int wm = (wave & 1) * 64, wn = (wave >> 1) * 64;
    f32x4 acc[4][4] = {};

    gemm_core(A, Bt, smem, m0, n0, t, acc);

    #pragma unroll
    for (int mi = 0; mi < 4; ++mi)
        #pragma unroll
        for (int ni = 0; ni < 4; ++ni) {
            int n = n0 + wn + ni * 16 + col;
            float bvv = bias[n];
            #pragma unroll
            for (int r = 0; r < 4; ++r) {
                int m = m0 + wm + mi * 16 + quad * 4 + r;
                C[(size_t)m * DIM + n] = acc[mi][ni][r] + bvv;
            }
        }
}

// ---------------- MFMA flash attention ----------------
// Q-tile 128/block (32 q/wave), K-block 64, double-buffered DMA staging,
// one-pass softmax with Q pre-scaled (p = exp2(St) directly).
// LPT dispatch: qt DESCENDING slow index, bh fast -> longest blocks start first
// on all CUs, short ones backfill (fixes R5's same-qt-per-CU stacking).
#define PSTR 72

__global__ __launch_bounds__(256) void attn_mfma(
    const ushort* __restrict__ Qg, const ushort* __restrict__ Kg,
    const ushort* __restrict__ Vtg, ushort* __restrict__ ctx)
{
    __shared__ ushort Ks[2][64 * 64];         // 2 x 8 KB, swizzled
    __shared__ ushort Vs[2][64 * 64];         // 2 x 8 KB, swizzled
    __shared__ ushort Ps[4][32 * PSTR];       // per-wave P / O staging, 18 KB

    const int t = threadIdx.x;
    const int lane = t & 63, wave = t >> 6;
    const int col = lane & 15, quad = lane >> 4;
    const int bh = blockIdx.x & 31;           // fast
    const int qt = 15 - (blockIdx.x >> 5);    // slow, descending: LPT
    const int b = bh >> 4, h = bh & 15;
    const ushort* Kp = Kg + ((size_t)bh << 17);
    const ushort* Vp = Vtg + ((size_t)bh << 17);
    ushort* Pw = Ps[wave];

    const int q0 = qt * 128;
    const int qw = q0 + wave * 32;

    // Q fragments (B-operand): 32 queries/wave, 2 col-tiles x 2 kk (pre-scaled)
    bh8 qf[2][2];
    #pragma unroll
    for (int ni = 0; ni < 2; ++ni) {
        const ushort* Qp = Qg + ((size_t)bh << 17) + ((size_t)(qw + ni * 16 + col) << 6) + quad * 8;
        qf[ni][0] = *(const bh8*)(Qp);
        qf[ni][1] = *(const bh8*)(Qp + 32);
    }
    float l0 = 0.f, l1 = 0.f;                 // per-lane partial sums (reduced at end)
    f32x4 O[4][2] = {};
    const int nIter = 2 * qt + 2;

    {   // stage iter 0 into buf 0
        #pragma unroll
        for (int j = 0; j < 2; ++j) {
            int C = wave * 128 + j * 64 + lane;
            int row = C >> 3;
            int lch = (C & 7) ^ (row & 7);
            async_cp16(&Kp[((size_t)row << 6) + lch * 8], &Ks[0][(wave * 128 + j * 64) * 8]);
            async_cp16(&Vp[((size_t)row << 11) + lch * 8], &Vs[0][(wave * 128 + j * 64) * 8]);
        }
    }

    #pragma unroll 1
    for (int it = 0; it < nIter; ++it) {
        const int kb = it * 64;
        __syncthreads();                       // buf(it&1) ready (drains DMA)
        if (it + 1 < nIter) {                  // prefetch next into other buf
            int kb2 = kb + 64;
            #pragma unroll
            for (int j = 0; j < 2; ++j) {
                int C = wave * 128 + j * 64 + lane;
                int row = C >> 3;
                int lch = (C & 7) ^ (row & 7);
                ushort* kd = &Ks[(it + 1) & 1][(wave * 128 + j * 64) * 8];
                ushort* vd = &Vs[(it + 1) & 1][(wave * 128 + j * 64) * 8];
                async_cp16(&Kp[((size_t)(kb2 + row) << 6) + lch * 8], kd);
                async_cp16(&Vp[((size_t)row << 11) + kb2 + lch * 8], vd);
            }
        }
        if (kb > qw + 31) continue;            // fully masked for this wave
        const ushort* Kb = Ks[it & 1];
        const ushort* Vb = Vs[it & 1];

        // St = K @ Q^T : row=key, col=query (already scaled via Q)
        f32x4 St[4][2] = {};
        #pragma unroll
        for (int kk = 0; kk < 2; ++kk) {
            int ph = ((kk * 4 + quad) ^ (col & 7)) * 8;
            #pragma unroll
            for (int kt = 0; kt < 4; ++kt) {
                bh8 kf = *(const bh8*)&Kb[(kt * 16 + col) * 64 + ph];
                #pragma unroll
                for (int ni = 0; ni < 2; ++ni)
                    St[kt][ni] = __builtin_amdgcn_mfma_f32_16x16x32_bf16(
                        kf, qf[ni][kk], St[kt][ni], 0, 0, 0);
            }
        }

        // causal mask: only near-diagonal blocks
        if (kb + 63 > qw) {
            #pragma unroll
            for (int ni = 0; ni < 2; ++ni) {
                int q_abs = qw + ni * 16 + col;
                #pragma unroll
                for (int kt = 0; kt < 4; ++kt)
                    #pragma unroll
                    for (int r = 0; r < 4; ++r)
                        if (kb + kt * 16 + quad * 4 + r > q_abs) St[kt][ni][r] = -1e30f;
            }
        }

        // one-pass softmax: p = exp2(s) (Q pre-scaled); per-lane partial l
        #pragma unroll
        for (int kt = 0; kt < 4; ++kt) {
            #pragma unroll
            for (int ni = 0; ni < 2; ++ni) {
                float p0 = exp2f(St[kt][ni][0]);
                float p1 = exp2f(St[kt][ni][1]);
                float p2 = exp2f(St[kt][ni][2]);
                float p3 = exp2f(St[kt][ni][3]);
                if (ni) l1 += (p0 + p1) + (p2 + p3);
                else    l0 += (p0 + p1) + (p2 + p3);
                ushort2 a01 = pk_bf16(p0, p1), a23 = pk_bf16(p2, p3);
                ushort4 pk4; pk4.x = a01.x; pk4.y = a01.y; pk4.z = a23.x; pk4.w = a23.y;
                *(ushort4*)&Pw[(ni * 16 + col) * PSTR + kt * 16 + quad * 4] = pk4;
            }
        }

        // ctx^T += V^T @ P^T (wave-local P, DS in-order: no barrier)
        #pragma unroll
        for (int kk = 0; kk < 2; ++kk) {
            int koff = kk * 32 + quad * 8;
            bh8 pf0 = *(const bh8*)&Pw[col * PSTR + koff];
            bh8 pf1 = *(const bh8*)&Pw[(16 + col) * PSTR + koff];
            int ph = ((kk * 4 + quad) ^ (col & 7)) * 8;
            #pragma unroll
            for (int dt = 0; dt < 4; ++dt) {
                bh8 vf = *(const bh8*)&Vb[(dt * 16 + col) * 64 + ph];
                O[dt][0] = __builtin_amdgcn_mfma_f32_16x16x32_bf16(vf, pf0, O[dt][0], 0, 0, 0);
                O[dt][1] = __builtin_amdgcn_mfma_f32_16x16x32_bf16(vf, pf1, O[dt][1], 0, 0, 0);
            }
        }
    }

    // deferred cross-lane l reduction (sum over the 4 quads)
    l0 += __shfl_xor(l0, 16); l0 += __shfl_xor(l0, 32);
    l1 += __shfl_xor(l1, 16); l1 += __shfl_xor(l1, 32);

    // epilogue: O (row=d, col=q) -> per-wave LDS [q][d] -> coalesced global
    float inv0 = 1.f / l0, inv1 = 1.f / l1;
    #pragma unroll
    for (int dt = 0; dt < 4; ++dt)
        #pragma unroll
        for (int ni = 0; ni < 2; ++ni) {
            float inv = ni ? inv1 : inv0;
            ushort2 a01 = pk_bf16(O[dt][ni][0] * inv, O[dt][ni][1] * inv);
            ushort2 a23 = pk_bf16(O[dt][ni][2] * inv, O[dt][ni][3] * inv);
            ushort4 pk4; pk4.x = a01.x; pk4.y = a01.y; pk4.z = a23.x; pk4.w = a23.y;
            *(ushort4*)&Pw[(ni * 16 + col) * PSTR + dt * 16 + quad * 4] = pk4;
        }
    #pragma unroll
    for (int i = 0; i < 4; ++i) {             // 256 chunks of 8, 4/lane
        int c = i * 64 + lane;
        int row = c >> 3, ko = (c & 7) * 8;
        *(uint4*)&ctx[((size_t)(b * SEQ) + qw + row) * DIM + (h << 6) + ko] =
            *(const uint4*)&Pw[row * PSTR + ko];
    }
}

// ---------------- launch ----------------
extern "C" void kernel_launch(void* const* d_in, const int* in_sizes, int n_in,
                              void* d_out, int out_size, void* d_ws, size_t ws_size,
                              hipStream_t stream) {
    const float* x  = (const float*)d_in[0];
    const float* Wq = (const float*)d_in[1];
    const float* bq = (const float*)d_in[2];
    const float* Wk = (const float*)d_in[3];
    const float* bk = (const float*)d_in[4];
    const float* Wv = (const float*)d_in[5];
    const float* bv = (const float*)d_in[6];
    const float* Wo = (const float*)d_in[7];
    const float* bo = (const float*)d_in[8];
    float* out = (float*)d_out;

    ushort* x_bf   = (ushort*)d_ws;              // 4M elems
    ushort* wq_t   = x_bf + 4194304;             // 1M each
    ushort* wk_t   = wq_t + 1048576;
    ushort* wv_t   = wk_t + 1048576;
    ushort* wo_t   = wv_t + 1048576;
    ushort* q_ws   = wo_t + 1048576;             // [B,H,S,64] 4M (pre-scaled)
    ushort* k_ws   = q_ws + 4194304;
    ushort* vt_ws  = k_ws + 4194304;             // [B,H,64,S] 4M
    ushort* ctx_ws = vt_ws + 4194304;            // [B,S,DIM]  4M

    dim3 pgrid(32, 32, 5);
    prep_inputs<<<pgrid, 256, 0, stream>>>(Wq, Wk, Wv, Wo, x,
                                           wq_t, wk_t, wv_t, wo_t, x_bf);

    dim3 qkv_grid(DIM / GTN, M_ROWS / GTM, 3);   // (8, 32, 3) = 768 blocks
    gemm_qkv<<<qkv_grid, 256, 0, stream>>>(x_bf, wq_t, wk_t, wv_t,
                                           bq, bk, bv, q_ws, k_ws, vt_ws);

    attn_mfma<<<BATCH * NUM_HEADS * 16, 256, 0, stream>>>(q_ws, k_ws, vt_ws, ctx_ws);

    dim3 ogrid(DIM / GTN, M_ROWS / GTM);         // (8, 32)
    gemm_out<<<ogrid, 256, 0, stream>>>(ctx_ws, wo_t, bo, out);
}

// Round 8
// 192.510 us; speedup vs baseline: 1.5483x; 1.1188x over previous
//
#include <hip/hip_runtime.h>
#include <hip/hip_bf16.h>

#define DIM 1024
#define NUM_HEADS 16
#define HEAD_DIM 64
#define BATCH 2
#define SEQ 2048
#define M_ROWS (BATCH * SEQ)   // 4096

typedef short bh8 __attribute__((ext_vector_type(8)));   // 8 bf16 (4 VGPRs)
typedef float f32x4 __attribute__((ext_vector_type(4)));

#define SCALE_Q 0.18033688011116016f   // 0.125 * log2(e), folded into Q projection

__device__ __forceinline__ ushort f2bf(float f) {
    union { float f; unsigned u; } v; v.f = f;
    unsigned u = v.u;
    unsigned r = (u + 0x7FFFu + ((u >> 16) & 1u)) >> 16;
    return (ushort)r;
}

__device__ __forceinline__ ushort2 pk_bf16(float a, float b) {
#if __has_builtin(__builtin_amdgcn_cvt_pk_bf16_f32)
    auto r = __builtin_amdgcn_cvt_pk_bf16_f32(a, b);
    ushort2 o; __builtin_memcpy(&o, &r, 4); return o;
#else
    ushort2 o; o.x = f2bf(a); o.y = f2bf(b); return o;
#endif
}

// async global->LDS 16B copy; LDS dest is wave-uniform base + lane*16
__device__ __forceinline__ void async_cp16(const ushort* g, ushort* l) {
    __builtin_amdgcn_global_load_lds(
        (const __attribute__((address_space(1))) void*)(uintptr_t)g,
        (__attribute__((address_space(3))) void*)(uint32_t)(uintptr_t)l,
        16, 0, 0);
}

// ------- fused prep: z<4 -> transpose+cast W_z [K,N]->[N,K] bf16; z==4 -> cast x -------
__global__ __launch_bounds__(256) void prep_inputs(
    const float* __restrict__ W0, const float* __restrict__ W1,
    const float* __restrict__ W2, const float* __restrict__ W3,
    const float* __restrict__ x,
    ushort* __restrict__ T0, ushort* __restrict__ T1,
    ushort* __restrict__ T2, ushort* __restrict__ T3,
    ushort* __restrict__ xb)
{
    const int z = blockIdx.z;
    const int t = threadIdx.x;
    if (z == 4) {
        int base = (blockIdx.y * 32 + blockIdx.x) * 1024 + t;   // float4 index
        const float4* in4 = (const float4*)x;
        ushort4* out4 = (ushort4*)xb;
        #pragma unroll
        for (int i = 0; i < 4; ++i) {
            float4 v = in4[base + i * 256];
            ushort4 o;
            o.x = f2bf(v.x); o.y = f2bf(v.y); o.z = f2bf(v.z); o.w = f2bf(v.w);
            out4[base + i * 256] = o;
        }
        return;
    }
    __shared__ float tile[32][33];
    const float* W = (z == 0) ? W0 : (z == 1) ? W1 : (z == 2) ? W2 : W3;
    ushort* Wt = (z == 0) ? T0 : (z == 1) ? T1 : (z == 2) ? T2 : T3;
    const int tx = t & 31, ty = t >> 5;            // ty 0..7
    const int k0 = blockIdx.y * 32, n0 = blockIdx.x * 32;
    #pragma unroll
    for (int i = 0; i < 4; ++i)
        tile[ty + 8 * i][tx] = W[(size_t)(k0 + ty + 8 * i) * DIM + n0 + tx];
    __syncthreads();
    #pragma unroll
    for (int i = 0; i < 4; ++i)
        Wt[(size_t)(n0 + ty + 8 * i) * DIM + k0 + tx] = f2bf(tile[tx][ty + 8 * i]);
}

// ---------------- shared MFMA GEMM core: 128x64 tile, BK=64 (R3-proven) ----------------
// C = A[M,1024] @ Bt[N,1024]^T. LDS dense + xor swizzle (chunk c at row r -> phys c^(r&7)).
#define GTM 128
#define GTN 64
#define GBK 64

__device__ __forceinline__ void gemm_core(
    const ushort* __restrict__ A, const ushort* __restrict__ Bt,
    ushort* smem, int m0, int n0, int t, f32x4 acc[4][2])
{
    ushort* As = smem;          // 128*64 = 8192 ushorts
    ushort* Bs = smem + 8192;   //  64*64 = 4096 ushorts
    const int lane = t & 63, wave = t >> 6;
    const int col = lane & 15, quad = lane >> 4;
    const int wm = (wave & 1) * 64, wn = (wave >> 1) * 32;

    for (int k0 = 0; k0 < DIM; k0 += GBK) {
        __syncthreads();
        #pragma unroll
        for (int j = 0; j < 4; ++j) {              // A: 1024 chunks, 4 issues/wave
            int C = wave * 256 + j * 64 + lane;
            int row = C >> 3;
            int lch = (C & 7) ^ (row & 7);
            async_cp16(&A[(size_t)(m0 + row) * DIM + k0 + lch * 8],
                       &As[(wave * 256 + j * 64) * 8]);
        }
        #pragma unroll
        for (int j = 0; j < 2; ++j) {              // B: 512 chunks, 2 issues/wave
            int C = wave * 128 + j * 64 + lane;
            int row = C >> 3;
            int lch = (C & 7) ^ (row & 7);
            async_cp16(&Bt[(size_t)(n0 + row) * DIM + k0 + lch * 8],
                       &Bs[(wave * 128 + j * 64) * 8]);
        }
        __syncthreads();
        #pragma unroll
        for (int kk = 0; kk < 2; ++kk) {
            bh8 af[4], bfr[2];
            #pragma unroll
            for (int mi = 0; mi < 4; ++mi) {
                int row = wm + mi * 16 + col;
                af[mi] = *(const bh8*)&As[row * 64 + (((kk * 4 + quad) ^ (row & 7)) * 8)];
            }
            #pragma unroll
            for (int ni = 0; ni < 2; ++ni) {
                int row = wn + ni * 16 + col;
                bfr[ni] = *(const bh8*)&Bs[row * 64 + (((kk * 4 + quad) ^ (row & 7)) * 8)];
            }
            #pragma unroll
            for (int mi = 0; mi < 4; ++mi)
                #pragma unroll
                for (int ni = 0; ni < 2; ++ni)
                    acc[mi][ni] = __builtin_amdgcn_mfma_f32_16x16x32_bf16(
                        af[mi], bfr[ni], acc[mi][ni], 0, 0, 0);
        }
    }
}

// ---------------- fused QKV projection ----------------
// z=0: Q (head layout, pre-scaled), z=1: K (head layout), z=2: V (transposed head layout)
__global__ __launch_bounds__(256) void gemm_qkv(
    const ushort* __restrict__ A,
    const ushort* __restrict__ WqT, const ushort* __restrict__ WkT,
    const ushort* __restrict__ WvT,
    const float* __restrict__ bq, const float* __restrict__ bk,
    const float* __restrict__ bv,
    ushort* __restrict__ qo, ushort* __restrict__ ko_, ushort* __restrict__ vo)
{
    __shared__ ushort smem[12288];   // 24 KB
    const int z = blockIdx.z;
    const ushort* Bt = (z == 0) ? WqT : (z == 1) ? WkT : WvT;
    const float* bias = (z == 0) ? bq : (z == 1) ? bk : bv;
    ushort* outp = (z == 0) ? qo : (z == 1) ? ko_ : vo;

    const int t = threadIdx.x;
    const int lane = t & 63, wave = t >> 6;
    const int col = lane & 15, quad = lane >> 4;
    const int m0 = blockIdx.y * GTM, n0 = blockIdx.x * GTN;
    const int wm = (wave & 1) * 64, wn = (wave >> 1) * 32;
    f32x4 acc[4][2] = {};

    gemm_core(A, Bt, smem, m0, n0, t, acc);

    const int b = m0 >> 11, s0 = m0 & (SEQ - 1);
    const int h = n0 >> 6;

    if (z < 2) {
        const float scl = (z == 0) ? SCALE_Q : 1.f;
        __syncthreads();
        ushort* LT = smem;                          // 128 x 72
        #pragma unroll
        for (int mi = 0; mi < 4; ++mi)
            #pragma unroll
            for (int ni = 0; ni < 2; ++ni) {
                int dl = wn + ni * 16 + col;
                float bvv = bias[n0 + dl];
                #pragma unroll
                for (int r = 0; r < 4; ++r) {
                    int ml = wm + mi * 16 + quad * 4 + r;
                    LT[ml * 72 + dl] = f2bf((acc[mi][ni][r] + bvv) * scl);
                }
            }
        __syncthreads();
        ushort* Cp = outp + (((size_t)(b * NUM_HEADS + h) * SEQ + s0) << 6);
        #pragma unroll
        for (int i = 0; i < 4; ++i) {
            int c = i * 256 + t;
            int row = c >> 3, ko = (c & 7) * 8;
            *(uint4*)&Cp[row * 64 + ko] = *(const uint4*)&LT[row * 72 + ko];
        }
    } else {
        // V transposed [B,H,64,S] via LDS transpose
        __syncthreads();
        ushort* LT = smem;                          // 64 x 136
        #pragma unroll
        for (int mi = 0; mi < 4; ++mi)
            #pragma unroll
            for (int ni = 0; ni < 2; ++ni) {
                int nl = wn + ni * 16 + col;
                float bvv = bias[n0 + nl];
                #pragma unroll
                for (int r = 0; r < 4; ++r) {
                    int ml = wm + mi * 16 + quad * 4 + r;
                    LT[nl * 136 + ml] = f2bf(acc[mi][ni][r] + bvv);
                }
            }
        __syncthreads();
        ushort* Cp = outp + (((size_t)(b * NUM_HEADS + h) * HEAD_DIM) << 11);
        #pragma unroll
        for (int i = 0; i < 4; ++i) {
            int c = i * 256 + t;
            int row = c >> 4, mo = (c & 15) * 8;
            *(uint4*)&Cp[((size_t)row << 11) + s0 + mo] = *(const uint4*)&LT[row * 136 + mo];
        }
    }
}

// ---------------- output projection: fp32 out ----------------
__global__ __launch_bounds__(256) void gemm_out(
    const ushort* __restrict__ A, const ushort* __restrict__ Bt,
    const float* __restrict__ bias, float* __restrict__ C)
{
    __shared__ ushort smem[12288];
    const int t = threadIdx.x;
    const int lane = t & 63, wave = t >> 6;
    const int col = lane & 15, quad = lane >> 4;
    const int m0 = blockIdx.y * GTM, n0 = blockIdx.x * GTN;
    const int wm = (wave & 1) * 64, wn = (wave >> 1) * 32;
    f32x4 acc[4][2] = {};

    gemm_core(A, Bt, smem, m0, n0, t, acc);

    #pragma unroll
    for (int mi = 0; mi < 4; ++mi)
        #pragma unroll
        for (int ni = 0; ni < 2; ++ni) {
            int n = n0 + wn + ni * 16 + col;
            float bvv = bias[n];
            #pragma unroll
            for (int r = 0; r < 4; ++r) {
                int m = m0 + wm + mi * 16 + quad * 4 + r;
                C[(size_t)m * DIM + n] = acc[mi][ni][r] + bvv;
            }
        }
}

// ---------------- MFMA flash attention: key-split waves, barrier-free K-loop ----------------
// Block = 64 queries (4 waves). Per 128-key iteration each wave owns a PRIVATE
// 32-key quarter: K/V fragments load directly global->VGPR (L2-resident),
// prefetched one iteration ahead. P transform is wave-local LDS (in-order DS).
// NO __syncthreads in the loop. Partial O per wave; 3-barrier LDS tree-reduce
// at the end. Grid 1024 (32 bh x 32 qt), LPT: qt descending.
#define PST 40   // P LDS row stride (ushorts), multiple of 8

__global__ __launch_bounds__(256, 2) void attn_mfma(
    const ushort* __restrict__ Qg, const ushort* __restrict__ Kg,
    const ushort* __restrict__ Vtg, ushort* __restrict__ ctx)
{
    __shared__ char smem[34304];
    float* OA   = (float*)smem;                    // 64x65 f32 = 16640 B
    float* OB   = (float*)(smem + 16640);          // 64x65 f32
    float* lbuf = (float*)(smem + 33280);          // 4x64 f32

    const int t = threadIdx.x;
    const int lane = t & 63, wave = t >> 6;
    const int col = lane & 15, quad = lane >> 4;
    const int bh = blockIdx.x & 31;                // fast
    const int qt = 31 - (blockIdx.x >> 5);         // slow, descending: LPT
    const int b = bh >> 4, h = bh & 15;
    const int q0 = qt * 64;
    const int kw0 = wave * 32;                     // wave's key offset in 128-span
    const ushort* Kp = Kg + ((size_t)bh << 17);
    const ushort* Vp = Vtg + ((size_t)bh << 17);
    ushort* Pw = (ushort*)smem + wave * 64 * PST;  // 5120 B/wave, inside [0,20480)

    // Q fragments (B-operand): 64 queries, 4 col-tiles x 2 kk (pre-scaled)
    bh8 qf[4][2];
    #pragma unroll
    for (int qi = 0; qi < 4; ++qi) {
        const ushort* Qp = Qg + ((size_t)bh << 17)
                         + ((size_t)(q0 + qi * 16 + col) << 6) + quad * 8;
        qf[qi][0] = *(const bh8*)(Qp);
        qf[qi][1] = *(const bh8*)(Qp + 32);
    }

    f32x4 O[4][4] = {};        // [dt][qi] partial over this wave's keys
    float l[4] = {0.f, 0.f, 0.f, 0.f};
    const int nIter = (q0 + 191) >> 7;             // ceil((q0+64)/128)

    // prefetch iter 0 K/V fragments (direct global->VGPR)
    bh8 kf_n[2][2], vf_n[4];
    #pragma unroll
    for (int kt = 0; kt < 2; ++kt)
        #pragma unroll
        for (int kk = 0; kk < 2; ++kk)
            kf_n[kt][kk] = *(const bh8*)&Kp[((size_t)(kw0 + kt * 16 + col) << 6) + kk * 32 + quad * 8];
    #pragma unroll
    for (int dt = 0; dt < 4; ++dt)
        vf_n[dt] = *(const bh8*)&Vp[((size_t)(dt * 16 + col) << 11) + kw0 + quad * 8];

    #pragma unroll 1
    for (int it = 0; it < nIter; ++it) {
        const int kb = it << 7;
        bh8 kf[2][2], vf[4];
        #pragma unroll
        for (int kt = 0; kt < 2; ++kt) { kf[kt][0] = kf_n[kt][0]; kf[kt][1] = kf_n[kt][1]; }
        #pragma unroll
        for (int dt = 0; dt < 4; ++dt) vf[dt] = vf_n[dt];

        if (it + 1 < nIter) {                      // prefetch next iteration
            const int kb2 = kb + 128;
            #pragma unroll
            for (int kt = 0; kt < 2; ++kt)
                #pragma unroll
                for (int kk = 0; kk < 2; ++kk)
                    kf_n[kt][kk] = *(const bh8*)&Kp[((size_t)(kb2 + kw0 + kt * 16 + col) << 6) + kk * 32 + quad * 8];
            #pragma unroll
            for (int dt = 0; dt < 4; ++dt)
                vf_n[dt] = *(const bh8*)&Vp[((size_t)(dt * 16 + col) << 11) + kb2 + kw0 + quad * 8];
        }

        if (kb + kw0 > q0 + 63) continue;          // this wave's quarter fully masked

        // St = K_w @ Q^T : [kt][qi], C-layout row=key_local(quad*4+r), col=q
        f32x4 St[2][4] = {};
        #pragma unroll
        for (int kk = 0; kk < 2; ++kk)
            #pragma unroll
            for (int kt = 0; kt < 2; ++kt)
                #pragma unroll
                for (int qi = 0; qi < 4; ++qi)
                    St[kt][qi] = __builtin_amdgcn_mfma_f32_16x16x32_bf16(
                        kf[kt][kk], qf[qi][kk], St[kt][qi], 0, 0, 0);

        // causal mask (only when this wave's keys can exceed some q)
        if (kb + kw0 + 31 > q0) {
            #pragma unroll
            for (int kt = 0; kt < 2; ++kt)
                #pragma unroll
                for (int qi = 0; qi < 4; ++qi) {
                    int q_abs = q0 + qi * 16 + col;
                    #pragma unroll
                    for (int r = 0; r < 4; ++r)
                        if (kb + kw0 + kt * 16 + quad * 4 + r > q_abs) St[kt][qi][r] = -1e30f;
                }
        }

        // p = exp2(s) (Q pre-scaled); write P^T to wave-local LDS [q][key_local]
        #pragma unroll
        for (int kt = 0; kt < 2; ++kt)
            #pragma unroll
            for (int qi = 0; qi < 4; ++qi) {
                float p0 = exp2f(St[kt][qi][0]);
                float p1 = exp2f(St[kt][qi][1]);
                float p2 = exp2f(St[kt][qi][2]);
                float p3 = exp2f(St[kt][qi][3]);
                l[qi] += (p0 + p1) + (p2 + p3);
                ushort2 a01 = pk_bf16(p0, p1), a23 = pk_bf16(p2, p3);
                ushort4 pk4; pk4.x = a01.x; pk4.y = a01.y; pk4.z = a23.x; pk4.w = a23.y;
                *(ushort4*)&Pw[(qi * 16 + col) * PST + kt * 16 + quad * 4] = pk4;
            }

        // O += V_w^T @ P  (A=V^T[d][key] from regs, B=P[key][q] from wave-local LDS)
        bh8 pf[4];
        #pragma unroll
        for (int qi = 0; qi < 4; ++qi)
            pf[qi] = *(const bh8*)&Pw[(qi * 16 + col) * PST + quad * 8];
        #pragma unroll
        for (int dt = 0; dt < 4; ++dt)
            #pragma unroll
            for (int qi = 0; qi < 4; ++qi)
                O[dt][qi] = __builtin_amdgcn_mfma_f32_16x16x32_bf16(
                    vf[dt], pf[qi], O[dt][qi], 0, 0, 0);
    }

    // ----- epilogue: cross-wave reduction -----
    // l: reduce within wave (cross-quad), publish per-wave totals
    #pragma unroll
    for (int qi = 0; qi < 4; ++qi) {
        l[qi] += __shfl_xor(l[qi], 16);
        l[qi] += __shfl_xor(l[qi], 32);
    }
    if (quad == 0) {
        #pragma unroll
        for (int qi = 0; qi < 4; ++qi)
            lbuf[wave * 64 + qi * 16 + col] = l[qi];
    }
    __syncthreads();   // #1: all waves done with K-loop (P region free), l published

    // O tree-reduction: (0+=1), (2+=3), then (0+=2)
    if (wave == 1 || wave == 3) {
        float* dst = (wave == 1) ? OA : OB;
        #pragma unroll
        for (int dt = 0; dt < 4; ++dt)
            #pragma unroll
            for (int qi = 0; qi < 4; ++qi)
                #pragma unroll
                for (int r = 0; r < 4; ++r)
                    dst[(dt * 16 + quad * 4 + r) * 65 + qi * 16 + col] = O[dt][qi][r];
    }
    __syncthreads();   // #2
    if (wave == 0 || wave == 2) {
        float* src = (wave == 0) ? OA : OB;
        #pragma unroll
        for (int dt = 0; dt < 4; ++dt)
            #pragma unroll
            for (int qi = 0; qi < 4; ++qi)
                #pragma unroll
                for (int r = 0; r < 4; ++r)
                    O[dt][qi][r] += src[(dt * 16 + quad * 4 + r) * 65 + qi * 16 + col];
    }
    __syncthreads();   // #3
    if (wave == 2) {
        #pragma unroll
        for (int dt = 0; dt < 4; ++dt)
            #pragma unroll
            for (int qi = 0; qi < 4; ++qi)
                #pragma unroll
                for (int r = 0; r < 4; ++r)
                    OA[(dt * 16 + quad * 4 + r) * 65 + qi * 16 + col] = O[dt][qi][r];
    }
    __syncthreads();   // #4
    if (wave == 0) {
        // final sum + normalize + store
        float inv[4];
        #pragma unroll
        for (int qi = 0; qi < 4; ++qi) {
            int idx = qi * 16 + col;
            float lt = lbuf[idx] + lbuf[64 + idx] + lbuf[128 + idx] + lbuf[192 + idx];
            inv[qi] = 1.f / lt;
        }
        ushort* Oq = (ushort*)(smem + 16640);      // 64 x 72 ushorts (reuse OB)
        #pragma unroll
        for (int dt = 0; dt < 4; ++dt)
            #pragma unroll
            for (int qi = 0; qi < 4; ++qi) {
                float s0 = (O[dt][qi][0] + OA[(dt * 16 + quad * 4 + 0) * 65 + qi * 16 + col]) * inv[qi];
                float s1 = (O[dt][qi][1] + OA[(dt * 16 + quad * 4 + 1) * 65 + qi * 16 + col]) * inv[qi];
                float s2 = (O[dt][qi][2] + OA[(dt * 16 + quad * 4 + 2) * 65 + qi * 16 + col]) * inv[qi];
                float s3 = (O[dt][qi][3] + OA[(dt * 16 + quad * 4 + 3) * 65 + qi * 16 + col]) * inv[qi];
                ushort2 a01 = pk_bf16(s0, s1), a23 = pk_bf16(s2, s3);
                ushort4 pk4; pk4.x = a01.x; pk4.y = a01.y; pk4.z = a23.x; pk4.w = a23.y;
                *(ushort4*)&Oq[(qi * 16 + col) * 72 + dt * 16 + quad * 4] = pk4;
            }
        // coalesced 16B stores: 512 chunks of 8 ushorts, 8 per lane (same-wave DS order)
        #pragma unroll
        for (int i = 0; i < 8; ++i) {
            int c = i * 64 + lane;
            int row = c >> 3, ko = (c & 7) * 8;
            *(uint4*)&ctx[((size_t)(b * SEQ) + q0 + row) * DIM + (h << 6) + ko] =
                *(const uint4*)&Oq[row * 72 + ko];
        }
    }
}

// ---------------- launch ----------------
extern "C" void kernel_launch(void* const* d_in, const int* in_sizes, int n_in,
                              void* d_out, int out_size, void* d_ws, size_t ws_size,
                              hipStream_t stream) {
    const float* x  = (const float*)d_in[0];
    const float* Wq = (const float*)d_in[1];
    const float* bq = (const float*)d_in[2];
    const float* Wk = (const float*)d_in[3];
    const float* bk = (const float*)d_in[4];
    const float* Wv = (const float*)d_in[5];
    const float* bv = (const float*)d_in[6];
    const float* Wo = (const float*)d_in[7];
    const float* bo = (const float*)d_in[8];
    float* out = (float*)d_out;

    ushort* x_bf   = (ushort*)d_ws;              // 4M elems
    ushort* wq_t   = x_bf + 4194304;             // 1M each
    ushort* wk_t   = wq_t + 1048576;
    ushort* wv_t   = wk_t + 1048576;
    ushort* wo_t   = wv_t + 1048576;
    ushort* q_ws   = wo_t + 1048576;             // [B,H,S,64] 4M (pre-scaled)
    ushort* k_ws   = q_ws + 4194304;
    ushort* vt_ws  = k_ws + 4194304;             // [B,H,64,S] 4M
    ushort* ctx_ws = vt_ws + 4194304;            // [B,S,DIM]  4M

    dim3 pgrid(32, 32, 5);
    prep_inputs<<<pgrid, 256, 0, stream>>>(Wq, Wk, Wv, Wo, x,
                                           wq_t, wk_t, wv_t, wo_t, x_bf);

    dim3 qkv_grid(DIM / GTN, M_ROWS / GTM, 3);   // (16, 32, 3) = 1536 blocks
    gemm_qkv<<<qkv_grid, 256, 0, stream>>>(x_bf, wq_t, wk_t, wv_t,
                                           bq, bk, bv, q_ws, k_ws, vt_ws);

    attn_mfma<<<BATCH * NUM_HEADS * 32, 256, 0, stream>>>(q_ws, k_ws, vt_ws, ctx_ws);

    dim3 ogrid(DIM / GTN, M_ROWS / GTM);         // (16, 32)
    gemm_out<<<ogrid, 256, 0, stream>>>(ctx_ws, wo_t, bo, out);
}